// Round 5
// baseline (448.289 us; speedup 1.0000x reference)
//
#include <hip/hip_runtime.h>
#include <cstdint>

typedef __bf16 bf16;
typedef __bf16 bf16x8 __attribute__((ext_vector_type(8)));
typedef __bf16 bf16x4 __attribute__((ext_vector_type(4)));
typedef float f32x4 __attribute__((ext_vector_type(4)));

#define DIMN 2048
#define SEQ  2048
#define NH   16
#define HD   128

// -------- async global->LDS 16B helper (m97 pattern) --------
__device__ __forceinline__ void gld_lds16(const bf16* g, bf16* l) {
    __builtin_amdgcn_global_load_lds(
        (const __attribute__((address_space(1))) void*)g,
        (__attribute__((address_space(3))) void*)l,
        16, 0, 0);
}

// -------- all fp32->bf16 casts in ONE launch --------
__global__ __launch_bounds__(256) void cast_all(
    const float* __restrict__ x,
    const float* __restrict__ wq, const float* __restrict__ wk,
    const float* __restrict__ wv, const float* __restrict__ wo,
    bf16* __restrict__ xb,
    bf16* __restrict__ wqb, bf16* __restrict__ wkb,
    bf16* __restrict__ wvb, bf16* __restrict__ wob)
{
    int id = blockIdx.x;
    const float* src; bf16* dst; int i;
    if (id < 8192) { src = x; dst = xb; i = id * 256 + threadIdx.x; }
    else {
        id -= 8192;
        int w = id >> 12; id &= 4095;
        src = (w == 0) ? wq : (w == 1) ? wk : (w == 2) ? wv : wo;
        dst = (w == 0) ? wqb : (w == 1) ? wkb : (w == 2) ? wvb : wob;
        i = id * 256 + threadIdx.x;
    }
    float4 v = ((const float4*)src)[i];
    bf16x4 o;
    o[0] = (bf16)v.x; o[1] = (bf16)v.y; o[2] = (bf16)v.z; o[3] = (bf16)v.w;
    ((bf16x4*)dst)[i] = o;
}

// -------- 128x128 m97-structure GEMM: output projection only --------
template<int OUT_F32>
__global__ __launch_bounds__(256) void gemm_bt(
    const bf16* __restrict__ A,
    const bf16* __restrict__ Bw0, const bf16* __restrict__ Bw1, const bf16* __restrict__ Bw2,
    const float* __restrict__ bias0, const float* __restrict__ bias1, const float* __restrict__ bias2,
    void* __restrict__ C0, void* __restrict__ C1, void* __restrict__ C2)
{
    const int K = DIMN, N = DIMN;
    const bf16* Bw = Bw0; const float* bias = bias0; void* Cout = C0;
    if (blockIdx.z == 1) { Bw = Bw1; bias = bias1; Cout = C1; }
    if (blockIdx.z == 2) { Bw = Bw2; bias = bias2; Cout = C2; }

    __shared__ __attribute__((aligned(16))) bf16 As[128 * 64];
    __shared__ __attribute__((aligned(16))) bf16 Bs[128 * 64];

    const int t    = threadIdx.x;
    const int lane = t & 63, wave = t >> 6;
    const int l15  = lane & 15, quad = lane >> 4;
    const int wm   = (wave >> 1) * 64, wn = (wave & 1) * 64;
    const long bm  = (long)blockIdx.y * 128;
    const long bn  = (long)blockIdx.x * 128;

    const bf16* agp[4]; const bf16* bgp[4]; bf16* asd[4]; bf16* bsd[4];
#pragma unroll
    for (int it = 0; it < 4; it++) {
        int fs  = it * 256 + t;
        int row = fs >> 3;
        int gs  = (fs & 7) ^ (row & 7);
        agp[it] = A  + (bm + row) * (long)K + gs * 8;
        bgp[it] = Bw + (bn + row) * (long)K + gs * 8;
        asd[it] = As + fs * 8;
        bsd[it] = Bs + fs * 8;
    }
    const int swl = l15 & 7;

    f32x4 acc[4][4] = {};

    for (int k0 = 0; k0 < K; k0 += 64) {
#pragma unroll
        for (int it = 0; it < 4; it++) {
            gld_lds16(agp[it] + k0, asd[it]);
            gld_lds16(bgp[it] + k0, bsd[it]);
        }
        __syncthreads();

#pragma unroll
        for (int ks2 = 0; ks2 < 2; ks2++) {
            const int sw = ((ks2 * 4 + quad) ^ swl) * 8;
            bf16x8 af[4], bfr[4];
#pragma unroll
            for (int i = 0; i < 4; i++)
                af[i] = *(const bf16x8*)(As + (wm + i * 16 + l15) * 64 + sw);
#pragma unroll
            for (int j = 0; j < 4; j++)
                bfr[j] = *(const bf16x8*)(Bs + (wn + j * 16 + l15) * 64 + sw);
#pragma unroll
            for (int i = 0; i < 4; i++)
#pragma unroll
                for (int j = 0; j < 4; j++)
                    acc[i][j] = __builtin_amdgcn_mfma_f32_16x16x32_bf16(af[i], bfr[j], acc[i][j], 0, 0, 0);
        }
        __syncthreads();
    }

#pragma unroll
    for (int j = 0; j < 4; j++) {
        const long col = bn + wn + j * 16 + l15;
        const float bv = bias[col];
#pragma unroll
        for (int i = 0; i < 4; i++) {
            const long row0 = bm + wm + i * 16 + quad * 4;
#pragma unroll
            for (int r = 0; r < 4; r++) {
                float v = acc[i][j][r] + bv;
                if (OUT_F32) ((float*)Cout)[(row0 + r) * N + col] = v;
                else         ((bf16*)Cout)[(row0 + r) * N + col] = (bf16)v;
            }
        }
    }
}

// ======== 256x256 8-phase GEMM v2 — deep-vmcnt schedule ========
// 8 waves (2M x 4N), per-wave C = 128x64, BK=64, LDS 128 KiB.
// Units: A-quads Aq0-3 (rows q*32+{0..31,128..159}), B-units B0-3 (rows u*64+{0..63}).
// Consumption: phase p reads Aq_p (+ all B at p==0, into regs held for the tile).
// Deep staging (issue->consume >= 4 phases):
//   t-p0: Aq0,Aq1(t+1)->buf^1   t-p1: Aq2,Aq3(t+1)->buf^1
//   t-p2: B0,B1(t+2) ->buf      t-p3: B2,B3(t+2)->buf   (B region free after t-p0)
// Waits (oldest-waited load always >=4 phases old):
//   end-p0: vmcnt(8)  end-p1: vmcnt(9)  end-p2: vmcnt(8)  end-p3: vmcnt(7)
// ONE barrier per phase (staged regions' last readers finished >=2 barriers prior).
#define VMCNT(n) asm volatile("s_waitcnt vmcnt(" #n ")" ::: "memory")

#define STAGE_AQ(bsel, kt, q) do {                                            \
    const int row_ = (q) * 32 + arow_base;                                    \
    gld_lds16(Ag + (long)row_ * DIMN + (kt) * 64 + ((ssg ^ (row_ & 7)) << 3), \
              &As[bsel][(row_ * 8 + ssg) * 8]);                               \
} while (0)

#define STAGE_BU(bsel, kt, u) do {                                            \
    const int row_ = (u) * 64 + srl;                                          \
    gld_lds16(Bg + (long)row_ * DIMN + (kt) * 64 + ((ssg ^ (row_ & 7)) << 3), \
              &Bs[bsel][(row_ * 8 + ssg) * 8]);                               \
} while (0)

#define PHASE(bsel, p0, STAGES, WAIT) do {                                    \
    bf16x8 af_[2][2];                                                         \
    _Pragma("unroll")                                                         \
    for (int im = 0; im < 2; ++im) {                                          \
        const int ar = wm * 128 + ((p0) * 2 + im) * 16 + l15;                 \
        _Pragma("unroll")                                                     \
        for (int ks = 0; ks < 2; ++ks)                                        \
            af_[im][ks] = *(const bf16x8*)(&As[bsel][(ar * 8 + ((ks * 4 + quad) ^ swl)) * 8]); \
    }                                                                         \
    if ((p0) == 0) {                                                          \
        _Pragma("unroll")                                                     \
        for (int j = 0; j < 4; ++j) {                                         \
            const int br = wn * 64 + j * 16 + l15;                            \
            _Pragma("unroll")                                                 \
            for (int ks = 0; ks < 2; ++ks)                                    \
                bfrag[j][ks] = *(const bf16x8*)(&Bs[bsel][(br * 8 + ((ks * 4 + quad) ^ swl)) * 8]); \
        }                                                                     \
    }                                                                         \
    STAGES;                                                                   \
    __builtin_amdgcn_s_setprio(1);                                            \
    _Pragma("unroll")                                                         \
    for (int im = 0; im < 2; ++im)                                            \
        _Pragma("unroll")                                                     \
        for (int j = 0; j < 4; ++j)                                           \
            _Pragma("unroll")                                                 \
            for (int ks = 0; ks < 2; ++ks)                                    \
                acc[(p0) * 2 + im][j] = __builtin_amdgcn_mfma_f32_16x16x32_bf16( \
                    af_[im][ks], bfrag[j][ks], acc[(p0) * 2 + im][j], 0, 0, 0); \
    __builtin_amdgcn_s_setprio(0);                                            \
    WAIT;                                                                     \
    asm volatile("" ::: "memory");                                            \
    __builtin_amdgcn_s_barrier();                                             \
    asm volatile("" ::: "memory");                                            \
} while (0)

__global__ __launch_bounds__(512, 2) void gemm256(
    const bf16* __restrict__ A,
    const bf16* __restrict__ Bw0, const bf16* __restrict__ Bw1, const bf16* __restrict__ Bw2,
    const float* __restrict__ bias0, const float* __restrict__ bias1, const float* __restrict__ bias2,
    bf16* __restrict__ C0, bf16* __restrict__ C1, bf16* __restrict__ C2)
{
    const int vtm = (blockIdx.z == 2);     // V^T mode (operand swap)
    const bf16* Ap; const bf16* Bp; const float* bias; bf16* Cout;
    if (blockIdx.z == 0)      { Ap = A;   Bp = Bw0; bias = bias0; Cout = C0; }
    else if (blockIdx.z == 1) { Ap = A;   Bp = Bw1; bias = bias1; Cout = C1; }
    else                      { Ap = Bw2; Bp = A;   bias = bias2; Cout = C2; }

    __shared__ __attribute__((aligned(16))) bf16 As[2][256 * 64];
    __shared__ __attribute__((aligned(16))) bf16 Bs[2][256 * 64];

    const int t    = threadIdx.x;
    const int lane = t & 63, wave = t >> 6;
    const int l15  = lane & 15, quad = lane >> 4;
    const int wm   = wave >> 2, wn = wave & 3;        // 2 x 4 wave grid
    const int swl  = l15 & 7;

    // bijective XCD swizzle per z-plane (128 wgs; plane size % 8 == 0)
    const int id  = blockIdx.y * 8 + blockIdx.x;
    const int wg  = (id & 7) * 16 + (id >> 3);
    const long bm_n = (long)(wg >> 3) * 256;   // 16 panels (4096)
    const long bn_n = (long)(wg & 7) * 256;    //  8 panels (2048)
    const long bm = vtm ? bn_n : bm_n;         // vtm: M over 2048 wv-rows
    const long bn = vtm ? bm_n : bn_n;         // vtm: N over 4096 x-rows

    const bf16* Ag = Ap + bm * DIMN;
    const bf16* Bg = Bp + bn * DIMN;

    // staging geometry: 512 threads x 16B = one 8KB unit (64 rows x 8 segs)
    const int srl = t >> 3, ssg = t & 7;
    const int arow_base = (srl & 31) + ((srl >> 5) << 7);   // 32 rows of each half

    f32x4  acc[8][4] = {};
    bf16x8 bfrag[4][2];

    // prologue: B(t0)->buf0, A(t0)->buf0, B(t1)->buf1 ; wait B(t0)+Aq0(t0) landed
    STAGE_BU(0, 0, 0); STAGE_BU(0, 0, 1); STAGE_BU(0, 0, 2); STAGE_BU(0, 0, 3);
    STAGE_AQ(0, 0, 0); STAGE_AQ(0, 0, 1); STAGE_AQ(0, 0, 2); STAGE_AQ(0, 0, 3);
    STAGE_BU(1, 1, 0); STAGE_BU(1, 1, 1); STAGE_BU(1, 1, 2); STAGE_BU(1, 1, 3);
    VMCNT(7);
    asm volatile("" ::: "memory");
    __builtin_amdgcn_s_barrier();
    asm volatile("" ::: "memory");

    for (int kt = 0; kt < 32; ++kt) {
        const int buf = kt & 1;
        const int tp1 = (kt + 1) & 31;     // wrap on tail: staged-but-never-read
        const int tp2 = (kt + 2) & 31;
        PHASE(buf, 0, { STAGE_AQ(buf ^ 1, tp1, 0); STAGE_AQ(buf ^ 1, tp1, 1); }, VMCNT(8));
        PHASE(buf, 1, { STAGE_AQ(buf ^ 1, tp1, 2); STAGE_AQ(buf ^ 1, tp1, 3); }, VMCNT(9));
        PHASE(buf, 2, { STAGE_BU(buf,     tp2, 0); STAGE_BU(buf,     tp2, 1); }, VMCNT(8));
        PHASE(buf, 3, { STAGE_BU(buf,     tp2, 2); STAGE_BU(buf,     tp2, 3); }, VMCNT(7));
    }

    if (vtm) {
        // C[m=wv-row][col=global x-row] -> vt[(b*DIMN+m)*SEQ + s]
#pragma unroll
        for (int j = 0; j < 4; ++j) {
            const long col = bn + wn * 64 + j * 16 + l15;
            const long cb = col >> 11, cs = col & (SEQ - 1);
#pragma unroll
            for (int i = 0; i < 8; ++i) {
                const long m0 = bm + wm * 128 + i * 16 + quad * 4;
#pragma unroll
                for (int r = 0; r < 4; ++r)
                    Cout[((cb * DIMN + m0 + r) * SEQ) + cs] =
                        (bf16)(acc[i][j][r] + bias[m0 + r]);
            }
        }
    } else {
#pragma unroll
        for (int j = 0; j < 4; ++j) {
            const long col = bn + wn * 64 + j * 16 + l15;
            const float bv = bias[col];
#pragma unroll
            for (int i = 0; i < 8; ++i) {
                const long row0 = bm + wm * 128 + i * 16 + quad * 4;
#pragma unroll
                for (int r = 0; r < 4; ++r)
                    Cout[(row0 + r) * DIMN + col] = (bf16)(acc[i][j][r] + bv);
            }
        }
    }
}

// -------- RMSNorm + RoPE on q,k --------
// Q pre-scale folds 1/sqrt(HD) * log2(e) so attention can use exp2f (bare v_exp_f32).
__global__ __launch_bounds__(256) void norm_prep(
    bf16* __restrict__ q, bf16* __restrict__ k,
    const float* __restrict__ gq, const float* __restrict__ gk,
    const float* __restrict__ freqs)
{
    const int id = blockIdx.x;
    const int t = threadIdx.x;
    const int qk  = id >> 12;
    const int row = id & 4095;                 // b*SEQ + s
    bf16* ptr = qk ? k : q;
    const float* g = qk ? gk : gq;
    const float osc = qk ? 1.0f : 0.12753138080219222f;  // (1/sqrt(128))*log2(e)
    const int s = row & (SEQ - 1);
    const int lane = t & 63, wave = t >> 6;

    bf16* base = ptr + (long)row * DIMN + t * 8;
    bf16x8 raw = *(const bf16x8*)base;
    float v[8]; float ss = 0.f;
#pragma unroll
    for (int j = 0; j < 8; j++) { v[j] = (float)raw[j]; ss += v[j] * v[j]; }
#pragma unroll
    for (int off = 32; off; off >>= 1) ss += __shfl_xor(ss, off, 64);
    __shared__ float red[4];
    if (lane == 0) red[wave] = ss;
    __syncthreads();
    float tot = red[0] + red[1] + red[2] + red[3];
    float rn = rsqrtf(tot * (1.0f / DIMN) + 1e-6f);

    const int e0 = t * 8;
    bf16x8 o;
#pragma unroll
    for (int pp = 0; pp < 4; pp++) {
        int e = e0 + pp * 2;
        float xr = v[pp * 2]     * rn * g[e];
        float xi = v[pp * 2 + 1] * rn * g[e + 1];
        int lc = (e >> 1) & 63;
        float cr = freqs[s * 128 + lc * 2];
        float ci = freqs[s * 128 + lc * 2 + 1];
        o[pp * 2]     = (bf16)((xr * cr - xi * ci) * osc);
        o[pp * 2 + 1] = (bf16)((xr * ci + xi * cr) * osc);
    }
    *(bf16x8*)base = o;
}

// -------- flash-style attention v3 + T5 setprio; exp2f (scale pre-folded) --------
__global__ __launch_bounds__(512, 2) void attention(
    const bf16* __restrict__ Q, const bf16* __restrict__ Kb,
    const bf16* __restrict__ Vt, bf16* __restrict__ O)
{
    __shared__ __attribute__((aligned(16))) bf16 Ksh[2][64 * 128];   // [kr][d], seg^=(kr&15)
    __shared__ __attribute__((aligned(16))) bf16 Vsh[2][128 * 64];   // [d][kr], seg^=(d&7)
    __shared__ __attribute__((aligned(16))) bf16 Psh[8][32 * 72];    // per-wave P[m][kr]
    __shared__ float Lsh[8][32];

    const int t = threadIdx.x;
    const int lane = t & 63, w = t >> 6;
    const int l15 = lane & 15, quad = lane >> 4;
    const int bh = blockIdx.x, b = bh >> 4, h = bh & 15;   // x = head: XCD-local K/V
    const int qt = blockIdx.y;
    const long qrow0 = (long)b * SEQ + qt * 256 + w * 32;
    const bf16* qbase = Q  + qrow0 * DIMN + h * HD;
    const bf16* kbase = Kb + (long)b * SEQ * DIMN + h * HD;
    const bf16* vbase = Vt + (long)bh * HD * SEQ;

    bf16x8 qf[2][4];
#pragma unroll
    for (int im = 0; im < 2; im++)
#pragma unroll
        for (int kd = 0; kd < 4; kd++)
            qf[im][kd] = *(const bf16x8*)(qbase + (long)(im * 16 + l15) * DIMN + kd * 32 + quad * 8);

    long koff[2], voff[2];
#pragma unroll
    for (int it = 0; it < 2; it++) {
        int fs = it * 512 + t;
        int kr = fs >> 4, kp = fs & 15;
        koff[it] = (long)kr * DIMN + (kp ^ (kr & 15)) * 8;
        int dr = fs >> 3, vp = fs & 7;
        voff[it] = (long)dr * SEQ + (vp ^ (dr & 7)) * 8;
    }

    f32x4 o_acc[2][8] = {};
    float Lt[2] = {0.f, 0.f};

#pragma unroll
    for (int it = 0; it < 2; it++) {
        gld_lds16(kbase + koff[it], &Ksh[0][(it * 512 + t) * 8]);
        gld_lds16(vbase + voff[it], &Vsh[0][(it * 512 + t) * 8]);
    }
    __syncthreads();

    for (int kt = 0; kt < 32; kt++) {
        const int cur = kt & 1;
        if (kt < 31) {
            const bf16* kg = kbase + (long)((kt + 1) * 64) * DIMN;
            const bf16* vg = vbase + (kt + 1) * 64;
#pragma unroll
            for (int it = 0; it < 2; it++) {
                gld_lds16(kg + koff[it], &Ksh[cur ^ 1][(it * 512 + t) * 8]);
                gld_lds16(vg + voff[it], &Vsh[cur ^ 1][(it * 512 + t) * 8]);
            }
        }
        const bf16* K0 = Ksh[cur];
        const bf16* V0 = Vsh[cur];

        // ---- S^T = K Q^T : D[kr][m] (Q pre-scaled by log2e/sqrt(d)) ----
        f32x4 st[4][2] = {};
        __builtin_amdgcn_s_setprio(1);
#pragma unroll
        for (int jk = 0; jk < 4; jk++)
#pragma unroll
            for (int kd = 0; kd < 4; kd++) {
                bf16x8 kf = *(const bf16x8*)(K0 + (jk * 16 + l15) * 128 + (((kd * 4 + quad) ^ l15) & 15) * 8);
                st[jk][0] = __builtin_amdgcn_mfma_f32_16x16x32_bf16(kf, qf[0][kd], st[jk][0], 0, 0, 0);
                st[jk][1] = __builtin_amdgcn_mfma_f32_16x16x32_bf16(kf, qf[1][kd], st[jk][1], 0, 0, 0);
            }
        __builtin_amdgcn_s_setprio(0);

        // ---- exp2 + P->LDS (b64) + per-lane partial L (reduction deferred) ----
#pragma unroll
        for (int im = 0; im < 2; im++) {
            float part = 0.f;
#pragma unroll
            for (int jk = 0; jk < 4; jk++) {
                bf16x4 pk;
#pragma unroll
                for (int r = 0; r < 4; r++) {
                    float e = exp2f(st[jk][im][r]);
                    part += e;
                    pk[r] = (bf16)e;
                }
                *(bf16x4*)(Psh[w] + (im * 16 + l15) * 72 + jk * 16 + quad * 4) = pk;
            }
            Lt[im] += part;
        }
        // no barrier: Psh[w] wave-private, LDS in-order per wave

        // ---- O += P V ----
        __builtin_amdgcn_s_setprio(1);
#pragma unroll
        for (int kd2 = 0; kd2 < 2; kd2++) {
            bf16x8 pa[2];
            pa[0] = *(const bf16x8*)(Psh[w] + (l15)      * 72 + kd2 * 32 + quad * 8);
            pa[1] = *(const bf16x8*)(Psh[w] + (16 + l15) * 72 + kd2 * 32 + quad * 8);
#pragma unroll
            for (int dj = 0; dj < 8; dj++) {
                bf16x8 vfr = *(const bf16x8*)(V0 + (dj * 16 + l15) * 64 + (((kd2 * 4 + quad) ^ l15) & 7) * 8);
                o_acc[0][dj] = __builtin_amdgcn_mfma_f32_16x16x32_bf16(pa[0], vfr, o_acc[0][dj], 0, 0, 0);
                o_acc[1][dj] = __builtin_amdgcn_mfma_f32_16x16x32_bf16(pa[1], vfr, o_acc[1][dj], 0, 0, 0);
            }
        }
        __builtin_amdgcn_s_setprio(0);
        __syncthreads();   // drains this iter's prefetch (overlapped) + releases cur buffer
    }

    // deferred L reduction over quads (butterfly: all lanes hold total for m=l15)
#pragma unroll
    for (int im = 0; im < 2; im++) {
        Lt[im] += __shfl_xor(Lt[im], 16, 64);
        Lt[im] += __shfl_xor(Lt[im], 32, 64);
    }
    if (quad == 0) { Lsh[w][l15] = Lt[0]; Lsh[w][16 + l15] = Lt[1]; }
    __syncthreads();

    // normalize + write (aliases Q buffer: block (qt,bh) writes only rows/cols it alone read)
#pragma unroll
    for (int im = 0; im < 2; im++)
#pragma unroll
        for (int r = 0; r < 4; r++) {
            float inv = 1.0f / Lsh[w][im * 16 + quad * 4 + r];
            long orow = qrow0 + im * 16 + quad * 4 + r;
#pragma unroll
            for (int dj = 0; dj < 8; dj++)
                O[orow * DIMN + h * HD + dj * 16 + l15] = (bf16)(o_acc[im][dj][r] * inv);
        }
}

extern "C" void kernel_launch(void* const* d_in, const int* in_sizes, int n_in,
                              void* d_out, int out_size, void* d_ws, size_t ws_size,
                              hipStream_t stream) {
    const float* x     = (const float*)d_in[0];
    const float* freqs = (const float*)d_in[1];
    const float* wq    = (const float*)d_in[2];
    const float* bq    = (const float*)d_in[3];
    const float* wk    = (const float*)d_in[4];
    const float* bk    = (const float*)d_in[5];
    const float* wv    = (const float*)d_in[6];
    const float* bv    = (const float*)d_in[7];
    const float* wo    = (const float*)d_in[8];
    const float* bo    = (const float*)d_in[9];
    const float* gq    = (const float*)d_in[10];
    const float* gk    = (const float*)d_in[11];
    float* out = (float*)d_out;

    const size_t MAT  = (size_t)4096 * 2048 * 2;   // 16 MiB
    const size_t WMAT = (size_t)2048 * 2048 * 2;   // 8 MiB
    char* p = (char*)d_ws;
    bf16* xb  = (bf16*)p; p += MAT;
    bf16* wqb = (bf16*)p; p += WMAT;
    bf16* wkb = (bf16*)p; p += WMAT;
    bf16* wvb = (bf16*)p; p += WMAT;
    bf16* wob = (bf16*)p; p += WMAT;
    bf16* qb  = (bf16*)p; p += MAT;
    bf16* kb  = (bf16*)p; p += MAT;
    bf16* vt  = (bf16*)p; p += MAT;
    bf16* attn = qb;   // alias (safe: per-block exclusive row/col regions)

    cast_all<<<24576, 256, 0, stream>>>(x, wq, wk, wv, wo, xb, wqb, wkb, wvb, wob);

    // Q, K, V^T in one 256^2 8-phase dispatch (z=2 writes vt via operand swap)
    gemm256<<<dim3(8, 16, 3), 512, 0, stream>>>(xb, wqb, wkb, wvb,
                                                bq, bk, bv, qb, kb, vt);

    norm_prep<<<8192, 256, 0, stream>>>(qb, kb, gq, gk, freqs);
    attention<<<dim3(32, 8), 512, 0, stream>>>(qb, kb, vt, attn);
    gemm_bt<1><<<dim3(16, 32, 1), 256, 0, stream>>>(attn, wob, wob, wob,
                                                    bo, bo, bo, out, out, out);
}

// Round 6
// 400.572 us; speedup vs baseline: 1.1191x; 1.1191x over previous
//
#include <hip/hip_runtime.h>
#include <cstdint>

typedef __bf16 bf16;
typedef __bf16 bf16x8 __attribute__((ext_vector_type(8)));
typedef __bf16 bf16x4 __attribute__((ext_vector_type(4)));
typedef float f32x4 __attribute__((ext_vector_type(4)));

#define DIMN 2048
#define SEQ  2048
#define NH   16
#define HD   128

// -------- async global->LDS 16B helper (m97 pattern) --------
__device__ __forceinline__ void gld_lds16(const bf16* g, bf16* l) {
    __builtin_amdgcn_global_load_lds(
        (const __attribute__((address_space(1))) void*)g,
        (__attribute__((address_space(3))) void*)l,
        16, 0, 0);
}

// -------- all fp32->bf16 casts in ONE launch --------
__global__ __launch_bounds__(256) void cast_all(
    const float* __restrict__ x,
    const float* __restrict__ wq, const float* __restrict__ wk,
    const float* __restrict__ wv, const float* __restrict__ wo,
    bf16* __restrict__ xb,
    bf16* __restrict__ wqb, bf16* __restrict__ wkb,
    bf16* __restrict__ wvb, bf16* __restrict__ wob)
{
    int id = blockIdx.x;
    const float* src; bf16* dst; int i;
    if (id < 8192) { src = x; dst = xb; i = id * 256 + threadIdx.x; }
    else {
        id -= 8192;
        int w = id >> 12; id &= 4095;
        src = (w == 0) ? wq : (w == 1) ? wk : (w == 2) ? wv : wo;
        dst = (w == 0) ? wqb : (w == 1) ? wkb : (w == 2) ? wvb : wob;
        i = id * 256 + threadIdx.x;
    }
    float4 v = ((const float4*)src)[i];
    bf16x4 o;
    o[0] = (bf16)v.x; o[1] = (bf16)v.y; o[2] = (bf16)v.z; o[3] = (bf16)v.w;
    ((bf16x4*)dst)[i] = o;
}

// -------- 128x128 m97-structure GEMM (845 TF on this shape; R3-verified).
// QKV: one z=3 dispatch. z=0: qb. z=1: kb. z=2: V^T via operand swap -> vt directly.
template<int OUT_F32>
__global__ __launch_bounds__(256) void gemm_bt(
    const bf16* __restrict__ A,
    const bf16* __restrict__ Bw0, const bf16* __restrict__ Bw1, const bf16* __restrict__ Bw2,
    const float* __restrict__ bias0, const float* __restrict__ bias1, const float* __restrict__ bias2,
    void* __restrict__ C0, void* __restrict__ C1, void* __restrict__ C2)
{
    const int K = DIMN, N = DIMN;
    const int vtm = (!OUT_F32) && (blockIdx.z == 2);   // V^T mode
    const bf16* Ap; const bf16* Bp; const float* bias; void* Cout;
    if (blockIdx.z == 0)      { Ap = A;   Bp = Bw0; bias = bias0; Cout = C0; }
    else if (blockIdx.z == 1) { Ap = A;   Bp = Bw1; bias = bias1; Cout = C1; }
    else                      { Ap = Bw2; Bp = A;   bias = bias2; Cout = C2; }

    __shared__ __attribute__((aligned(16))) bf16 As[128 * 64];
    __shared__ __attribute__((aligned(16))) bf16 Bs[128 * 64];

    const int t    = threadIdx.x;
    const int lane = t & 63, wave = t >> 6;
    const int l15  = lane & 15, quad = lane >> 4;
    const int wm   = (wave >> 1) * 64, wn = (wave & 1) * 64;
    const long bm = vtm ? (long)blockIdx.x * 128 : (long)blockIdx.y * 128;
    const long bn = vtm ? (long)blockIdx.y * 128 : (long)blockIdx.x * 128;

    const bf16* agp[4]; const bf16* bgp[4]; bf16* asd[4]; bf16* bsd[4];
#pragma unroll
    for (int it = 0; it < 4; it++) {
        int fs  = it * 256 + t;
        int row = fs >> 3;
        int gs  = (fs & 7) ^ (row & 7);
        agp[it] = Ap + (bm + row) * (long)K + gs * 8;
        bgp[it] = Bp + (bn + row) * (long)K + gs * 8;
        asd[it] = As + fs * 8;
        bsd[it] = Bs + fs * 8;
    }
    const int swl = l15 & 7;

    f32x4 acc[4][4] = {};

    for (int k0 = 0; k0 < K; k0 += 64) {
#pragma unroll
        for (int it = 0; it < 4; it++) {
            gld_lds16(agp[it] + k0, asd[it]);
            gld_lds16(bgp[it] + k0, bsd[it]);
        }
        __syncthreads();

#pragma unroll
        for (int ks2 = 0; ks2 < 2; ks2++) {
            const int sw = ((ks2 * 4 + quad) ^ swl) * 8;
            bf16x8 af[4], bfr[4];
#pragma unroll
            for (int i = 0; i < 4; i++)
                af[i] = *(const bf16x8*)(As + (wm + i * 16 + l15) * 64 + sw);
#pragma unroll
            for (int j = 0; j < 4; j++)
                bfr[j] = *(const bf16x8*)(Bs + (wn + j * 16 + l15) * 64 + sw);
#pragma unroll
            for (int i = 0; i < 4; i++)
#pragma unroll
                for (int j = 0; j < 4; j++)
                    acc[i][j] = __builtin_amdgcn_mfma_f32_16x16x32_bf16(af[i], bfr[j], acc[i][j], 0, 0, 0);
        }
        __syncthreads();
    }

    if (vtm) {
#pragma unroll
        for (int j = 0; j < 4; j++) {
            const long col = bn + wn + j * 16 + l15;
            const long cb = col >> 11, cs = col & (SEQ - 1);
#pragma unroll
            for (int i = 0; i < 4; i++) {
                const long m0 = bm + wm + i * 16 + quad * 4;
#pragma unroll
                for (int r = 0; r < 4; r++)
                    ((bf16*)Cout)[((cb * DIMN + m0 + r) * SEQ) + cs] =
                        (bf16)(acc[i][j][r] + bias[m0 + r]);
            }
        }
    } else {
#pragma unroll
        for (int j = 0; j < 4; j++) {
            const long col = bn + wn + j * 16 + l15;
            const float bv = bias[col];
#pragma unroll
            for (int i = 0; i < 4; i++) {
                const long row0 = bm + wm + i * 16 + quad * 4;
#pragma unroll
                for (int r = 0; r < 4; r++) {
                    float v = acc[i][j][r] + bv;
                    if (OUT_F32) ((float*)Cout)[(row0 + r) * N + col] = v;
                    else         ((bf16*)Cout)[(row0 + r) * N + col] = (bf16)v;
                }
            }
        }
    }
}

// -------- RMSNorm + RoPE on q,k --------
// Q pre-scale folds 1/sqrt(HD) * log2(e) so attention can use exp2f (bare v_exp_f32).
__global__ __launch_bounds__(256) void norm_prep(
    bf16* __restrict__ q, bf16* __restrict__ k,
    const float* __restrict__ gq, const float* __restrict__ gk,
    const float* __restrict__ freqs)
{
    const int id = blockIdx.x;
    const int t = threadIdx.x;
    const int qk  = id >> 12;
    const int row = id & 4095;                 // b*SEQ + s
    bf16* ptr = qk ? k : q;
    const float* g = qk ? gk : gq;
    const float osc = qk ? 1.0f : 0.12753138080219222f;  // (1/sqrt(128))*log2(e)
    const int s = row & (SEQ - 1);
    const int lane = t & 63, wave = t >> 6;

    bf16* base = ptr + (long)row * DIMN + t * 8;
    bf16x8 raw = *(const bf16x8*)base;
    float v[8]; float ss = 0.f;
#pragma unroll
    for (int j = 0; j < 8; j++) { v[j] = (float)raw[j]; ss += v[j] * v[j]; }
#pragma unroll
    for (int off = 32; off; off >>= 1) ss += __shfl_xor(ss, off, 64);
    __shared__ float red[4];
    if (lane == 0) red[wave] = ss;
    __syncthreads();
    float tot = red[0] + red[1] + red[2] + red[3];
    float rn = rsqrtf(tot * (1.0f / DIMN) + 1e-6f);

    const int e0 = t * 8;
    bf16x8 o;
#pragma unroll
    for (int pp = 0; pp < 4; pp++) {
        int e = e0 + pp * 2;
        float xr = v[pp * 2]     * rn * g[e];
        float xi = v[pp * 2 + 1] * rn * g[e + 1];
        int lc = (e >> 1) & 63;
        float cr = freqs[s * 128 + lc * 2];
        float ci = freqs[s * 128 + lc * 2 + 1];
        o[pp * 2]     = (bf16)((xr * cr - xi * ci) * osc);
        o[pp * 2 + 1] = (bf16)((xr * ci + xi * cr) * osc);
    }
    *(bf16x8*)base = o;
}

// ======== attention v4: in-register P (no Psh) -> 64 KiB LDS -> 2 blocks/CU ========
// 8 waves x 16 q-rows = 128 q-rows/block; grid (32 bh, 16 qt) = 512 blocks = 2/CU.
// P exchange: st[jk][r] = P[m=l15][kr=jk*16+quad*4+r]; PV needs A-frag
// pa[kd2] = P[l15][kd2*32+quad*8+j]. Mapping: jk_s = kd2*2+(quad>>1),
// quad_s = (quad&1)*2+(j>>2), r_s = j&3 -> pure permutation across the 4 quads
// sharing l15. Implemented: cvt_pk (f32x2->bf16x2 word) + 16 ds_bpermute/kt
// (g-split so every bpermute's source register index is compile-time static).
__global__ __launch_bounds__(512, 4) void attention(
    const bf16* __restrict__ Q, const bf16* __restrict__ Kb,
    const bf16* __restrict__ Vt, bf16* __restrict__ O)
{
    __shared__ __attribute__((aligned(16))) bf16 Ksh[2][64 * 128];   // [kr][d], seg^=(kr&15)
    __shared__ __attribute__((aligned(16))) bf16 Vsh[2][128 * 64];   // [d][kr], seg^=(d&7)

    const int t = threadIdx.x;
    const int lane = t & 63, w = t >> 6;
    const int l15 = lane & 15, quad = lane >> 4;
    const int hi = quad >> 1;
    const int bh = blockIdx.x, b = bh >> 4, h = bh & 15;   // x = head: XCD-local K/V
    const int qt = blockIdx.y;                             // 0..15 (128 rows each)
    const long qrow0 = (long)b * SEQ + qt * 128 + w * 16;
    const bf16* qbase = Q  + qrow0 * DIMN + h * HD;
    const bf16* kbase = Kb + (long)b * SEQ * DIMN + h * HD;
    const bf16* vbase = Vt + (long)bh * HD * SEQ;

    // Q fragments resident (pre-scaled by norm_prep): B[m=l15][k=quad*8+j]
    bf16x8 qf[4];
#pragma unroll
    for (int kd = 0; kd < 4; kd++)
        qf[kd] = *(const bf16x8*)(qbase + (long)l15 * DIMN + kd * 32 + quad * 8);

    long koff[2], voff[2];
#pragma unroll
    for (int it = 0; it < 2; it++) {
        int fs = it * 512 + t;
        int kr = fs >> 4, kp = fs & 15;
        koff[it] = (long)kr * DIMN + (kp ^ (kr & 15)) * 8;
        int dr = fs >> 3, vp = fs & 7;
        voff[it] = (long)dr * SEQ + (vp ^ (dr & 7)) * 8;
    }

    // bpermute byte indices for the two source quads of this lane
    const int srcA = (((quad & 1) * 2) * 16 + l15) * 4;
    const int srcB = srcA + 64;

    f32x4 o_acc[8] = {};
    float Lt = 0.f;

#pragma unroll
    for (int it = 0; it < 2; it++) {
        gld_lds16(kbase + koff[it], &Ksh[0][(it * 512 + t) * 8]);
        gld_lds16(vbase + voff[it], &Vsh[0][(it * 512 + t) * 8]);
    }
    __syncthreads();

    for (int kt = 0; kt < 32; kt++) {
        const int cur = kt & 1;
        if (kt < 31) {
            const bf16* kg = kbase + (long)((kt + 1) * 64) * DIMN;
            const bf16* vg = vbase + (kt + 1) * 64;
#pragma unroll
            for (int it = 0; it < 2; it++) {
                gld_lds16(kg + koff[it], &Ksh[cur ^ 1][(it * 512 + t) * 8]);
                gld_lds16(vg + voff[it], &Vsh[cur ^ 1][(it * 512 + t) * 8]);
            }
        }
        const bf16* K0 = Ksh[cur];
        const bf16* V0 = Vsh[cur];

        // ---- S^T = K Q^T : st[jk] = P-pre[m=l15][kr=jk*16+quad*4+r] ----
        f32x4 st[4] = {};
        __builtin_amdgcn_s_setprio(1);
#pragma unroll
        for (int jk = 0; jk < 4; jk++)
#pragma unroll
            for (int kd = 0; kd < 4; kd++) {
                bf16x8 kf = *(const bf16x8*)(K0 + (jk * 16 + l15) * 128 + (((kd * 4 + quad) ^ l15) & 15) * 8);
                st[jk] = __builtin_amdgcn_mfma_f32_16x16x32_bf16(kf, qf[kd], st[jk], 0, 0, 0);
            }
        __builtin_amdgcn_s_setprio(0);

        // ---- exp2 + pack to bf16 words + L partial ----
        uint32_t pk0[4], pk1[4];
#pragma unroll
        for (int jk = 0; jk < 4; jk++) {
            float e0 = exp2f(st[jk][0]);
            float e1 = exp2f(st[jk][1]);
            float e2 = exp2f(st[jk][2]);
            float e3 = exp2f(st[jk][3]);
            Lt += (e0 + e1) + (e2 + e3);
            uint32_t lo, hiw;
            asm("v_cvt_pk_bf16_f32 %0, %1, %2" : "=v"(lo)  : "v"(e0), "v"(e1));
            asm("v_cvt_pk_bf16_f32 %0, %1, %2" : "=v"(hiw) : "v"(e2), "v"(e3));
            pk0[jk] = lo; pk1[jk] = hiw;
        }

        // ---- in-register P redistribute (16 bpermute) + O += P V ----
        __builtin_amdgcn_s_setprio(1);
#pragma unroll
        for (int kd2 = 0; kd2 < 2; kd2++) {
            int a0 = __builtin_amdgcn_ds_bpermute(srcA, (int)pk0[kd2 * 2]);
            int a1 = __builtin_amdgcn_ds_bpermute(srcA, (int)pk0[kd2 * 2 + 1]);
            int b0 = __builtin_amdgcn_ds_bpermute(srcA, (int)pk1[kd2 * 2]);
            int b1 = __builtin_amdgcn_ds_bpermute(srcA, (int)pk1[kd2 * 2 + 1]);
            int c0 = __builtin_amdgcn_ds_bpermute(srcB, (int)pk0[kd2 * 2]);
            int c1 = __builtin_amdgcn_ds_bpermute(srcB, (int)pk0[kd2 * 2 + 1]);
            int d0 = __builtin_amdgcn_ds_bpermute(srcB, (int)pk1[kd2 * 2]);
            int d1 = __builtin_amdgcn_ds_bpermute(srcB, (int)pk1[kd2 * 2 + 1]);
            union { uint32_t u[4]; bf16x8 v; } pu;
            pu.u[0] = hi ? (uint32_t)a1 : (uint32_t)a0;   // j=0,1  (pk0 @ srcA)
            pu.u[1] = hi ? (uint32_t)b1 : (uint32_t)b0;   // j=2,3  (pk1 @ srcA)
            pu.u[2] = hi ? (uint32_t)c1 : (uint32_t)c0;   // j=4,5  (pk0 @ srcB)
            pu.u[3] = hi ? (uint32_t)d1 : (uint32_t)d0;   // j=6,7  (pk1 @ srcB)
            bf16x8 pa = pu.v;
#pragma unroll
            for (int dj = 0; dj < 8; dj++) {
                bf16x8 vfr = *(const bf16x8*)(V0 + (dj * 16 + l15) * 64 + (((kd2 * 4 + quad) ^ l15) & 7) * 8);
                o_acc[dj] = __builtin_amdgcn_mfma_f32_16x16x32_bf16(pa, vfr, o_acc[dj], 0, 0, 0);
            }
        }
        __builtin_amdgcn_s_setprio(0);
        __syncthreads();   // drains this iter's prefetch (overlapped) + releases cur buffer
    }

    // L: butterfly over the 4 quads sharing l15 -> all lanes hold L[m=l15]
    Lt += __shfl_xor(Lt, 16, 64);
    Lt += __shfl_xor(Lt, 32, 64);

    // normalize + write (aliases Q buffer: block (qt,bh) writes only rows/cols it alone read)
#pragma unroll
    for (int r = 0; r < 4; r++) {
        float Lr = __shfl(Lt, quad * 4 + r, 64);   // L for row m = quad*4+r
        float inv = 1.0f / Lr;
        long orow = qrow0 + quad * 4 + r;
#pragma unroll
        for (int dj = 0; dj < 8; dj++)
            O[orow * DIMN + h * HD + dj * 16 + l15] = (bf16)(o_acc[dj][r] * inv);
    }
}

extern "C" void kernel_launch(void* const* d_in, const int* in_sizes, int n_in,
                              void* d_out, int out_size, void* d_ws, size_t ws_size,
                              hipStream_t stream) {
    const float* x     = (const float*)d_in[0];
    const float* freqs = (const float*)d_in[1];
    const float* wq    = (const float*)d_in[2];
    const float* bq    = (const float*)d_in[3];
    const float* wk    = (const float*)d_in[4];
    const float* bk    = (const float*)d_in[5];
    const float* wv    = (const float*)d_in[6];
    const float* bv    = (const float*)d_in[7];
    const float* wo    = (const float*)d_in[8];
    const float* bo    = (const float*)d_in[9];
    const float* gq    = (const float*)d_in[10];
    const float* gk    = (const float*)d_in[11];
    float* out = (float*)d_out;

    const size_t MAT  = (size_t)4096 * 2048 * 2;   // 16 MiB
    const size_t WMAT = (size_t)2048 * 2048 * 2;   // 8 MiB
    char* p = (char*)d_ws;
    bf16* xb  = (bf16*)p; p += MAT;
    bf16* wqb = (bf16*)p; p += WMAT;
    bf16* wkb = (bf16*)p; p += WMAT;
    bf16* wvb = (bf16*)p; p += WMAT;
    bf16* wob = (bf16*)p; p += WMAT;
    bf16* qb  = (bf16*)p; p += MAT;
    bf16* kb  = (bf16*)p; p += MAT;
    bf16* vt  = (bf16*)p; p += MAT;
    bf16* attn = qb;   // alias (safe: per-block exclusive row/col regions)

    cast_all<<<24576, 256, 0, stream>>>(x, wq, wk, wv, wo, xb, wqb, wkb, wvb, wob);

    // Q, K, V^T in one dispatch (z=2 writes vt directly via operand swap)
    gemm_bt<0><<<dim3(16, 32, 3), 256, 0, stream>>>(xb, wqb, wkb, wvb,
                                                    bq, bk, bv, qb, kb, vt);

    norm_prep<<<8192, 256, 0, stream>>>(qb, kb, gq, gk, freqs);
    attention<<<dim3(32, 16), 512, 0, stream>>>(qb, kb, vt, attn);
    gemm_bt<1><<<dim3(16, 32, 1), 256, 0, stream>>>(attn, wob, wob, wob,
                                                    bo, bo, bo, out, out, out);
}